// Round 5
// baseline (191.882 us; speedup 1.0000x reference)
//
#include <hip/hip_runtime.h>

typedef _Float16 f16;
typedef _Float16 f16x8 __attribute__((ext_vector_type(8)));
typedef _Float16 f16x4 __attribute__((ext_vector_type(4)));
typedef float f32x4 __attribute__((ext_vector_type(4)));

#define B_TOT 128
#define T_LEN 512
#define D_DIM 256
#define H_DIM 512

// ---------------- helpers ----------------
__device__ __forceinline__ void gload_lds16(const void* g, void* l) {
  __builtin_amdgcn_global_load_lds(
      (const __attribute__((address_space(1))) void*)g,
      (__attribute__((address_space(3))) void*)l, 16, 0, 0);
}

__device__ __forceinline__ float rcpf(float x) { return __builtin_amdgcn_rcpf(x); }

// ---------------- kernel 1: weight convert + transpose ----------------
// W[k][n] f32 (256x512) -> Wt[n][k] f16 (512x256), 3 weights
__global__ void __launch_bounds__(256) cvt_w(const float* __restrict__ Wr,
                                             const float* __restrict__ Wz,
                                             const float* __restrict__ Wh,
                                             f16* __restrict__ Wt) {
  int idx = blockIdx.x * 256 + threadIdx.x;      // < 3*131072
  int w = idx >> 17;
  int rem = idx & 131071;
  int n = rem >> 8;        // 0..511
  int k = rem & 255;       // 0..255
  const float* W = (w == 0) ? Wr : ((w == 1) ? Wz : Wh);
  Wt[(size_t)w * 131072 + n * 256 + k] = (f16)W[k * 512 + n];
}

// ---------------- kernel 2: fused 3-weight GEMM (cvt_x fused in) ----------------
// X32 [M][256] f32 (raw input), Wt [512][256] f16 (pre-transposed).
// P output layout CHUNKED: P[bb][tg(64)][h(512)][8t] f16.
// BM=128, BN=64 (x3 weights), BK=64, 4 K-iterations, double-buffered LDS.
// LDS per buffer (40 KB): A [p(8)][128 rows][16B] f16, B [w(3)][p(8)][64][16B].
// A is reg-staged from f32 (issue-early, cvt+ds_write-late, T14);
// B is gload_lds prefetched.
__global__ void __launch_bounds__(256, 2) brc_gemm3(
    const float* __restrict__ X32,
    const f16* __restrict__ Wr, const f16* __restrict__ Wz, const f16* __restrict__ Wh,
    f16* __restrict__ Pr, f16* __restrict__ Pz, f16* __restrict__ Ph,
    int Mtiles) {
  __shared__ char lds[81920];          // 2 x 40 KB buffers
  const int tid = threadIdx.x;
  const int wid = tid >> 6, lane = tid & 63;
  // bijective XCD swizzle; consecutive lids (sharing an X tile) on one XCD
  const int bid = blockIdx.x;
  const int lid = (bid & 7) * Mtiles + (bid >> 3);   // grid = Mtiles*8
  const int mt = lid >> 3, nt = lid & 7;             // m-major
  const int m0 = mt * 128, n0 = nt * 64;
  const int wr = wid >> 1, wc = wid & 1;             // 2x2 waves, tile 64x32

  // A staging: thread -> (row r_ = tid>>1, k-half half_ = tid&1)
  const int r_ = tid >> 1, half_ = tid & 1;
  const char* Xrow = (const char*)X32 + ((size_t)(m0 + r_)) * 1024 + half_ * 128;
  const char* WrC = (const char*)Wr + (size_t)n0 * 512;
  const char* WzC = (const char*)Wz + (size_t)n0 * 512;
  const char* WhC = (const char*)Wh + (size_t)n0 * 512;

  f32x4 acc[3][4][2] = {};
  float4 av[8];

  // issue 8 dwordx4 f32 loads of A k-slice kt into av
#define LOAD_A(kt)                                                            \
  do {                                                                        \
    _Pragma("unroll") for (int j = 0; j < 8; ++j)                             \
      av[j] = *(const float4*)(Xrow + (kt) * 256 + j * 16);                   \
  } while (0)

  // cvt av -> f16 and write to A region of buffer buf (k-plane layout)
#define WRITE_A(buf)                                                          \
  do {                                                                        \
    char* lb_ = lds + (buf) * 40960;                                          \
    _Pragma("unroll") for (int q = 0; q < 4; ++q) {                           \
      f16x8 hv;                                                               \
      const float* fp_ = (const float*)&av[q * 2];                            \
      _Pragma("unroll") for (int e = 0; e < 8; ++e) hv[e] = (f16)fp_[e];      \
      *(f16x8*)(lb_ + (half_ * 4 + q) * 2048 + r_ * 16) = hv;                 \
    }                                                                         \
  } while (0)

  // stage B K-tile kt into buffer buf: 6 gload_lds per thread
#define STAGE_B(kt, buf)                                                      \
  do {                                                                        \
    char* lb_ = lds + (buf) * 40960 + 16384;                                  \
    _Pragma("unroll") for (int c = 0; c < 6; ++c) {                           \
      int id_ = c * 4 + wid, w3_ = id_ >> 3, p_ = id_ & 7;                    \
      const char* W_ = (w3_ == 0) ? WrC : ((w3_ == 1) ? WzC : WhC);           \
      gload_lds16(W_ + (size_t)lane * 512 + (kt) * 128 + p_ * 16,             \
                  lb_ + w3_ * 8192 + p_ * 1024);                              \
    }                                                                         \
  } while (0)

  // prologue: tile 0
  LOAD_A(0);
  STAGE_B(0, 0);
  WRITE_A(0);                // compiler inserts vmcnt wait for av here
  __syncthreads();

  const int kq = lane >> 4, rl = lane & 15;
  for (int kt = 0; kt < 4; ++kt) {
    if (kt < 3) {
      LOAD_A(kt + 1);                      // issue-early: f32 A loads in flight
      STAGE_B(kt + 1, (kt + 1) & 1);       // B prefetch via gload_lds
    }
    __builtin_amdgcn_sched_barrier(0);     // keep issues above the compute
    const char* lb = lds + (kt & 1) * 40960;
    __builtin_amdgcn_s_setprio(1);
#pragma unroll
    for (int kk = 0; kk < 2; ++kk) {
      f16x8 a[4], b[3][2];
#pragma unroll
      for (int mi = 0; mi < 4; ++mi)
        a[mi] = *(const f16x8*)(lb + (kk * 4 + kq) * 2048 +
                                (wr * 64 + mi * 16 + rl) * 16);
#pragma unroll
      for (int w = 0; w < 3; ++w)
#pragma unroll
        for (int ni = 0; ni < 2; ++ni)
          b[w][ni] = *(const f16x8*)(lb + 16384 + w * 8192 + (kk * 4 + kq) * 1024 +
                                     (wc * 32 + ni * 16 + rl) * 16);
#pragma unroll
      for (int w = 0; w < 3; ++w)
#pragma unroll
        for (int mi = 0; mi < 4; ++mi)
#pragma unroll
          for (int ni = 0; ni < 2; ++ni)
            acc[w][mi][ni] = __builtin_amdgcn_mfma_f32_16x16x32_f16(
                a[mi], b[w][ni], acc[w][mi][ni], 0, 0, 0);
    }
    __builtin_amdgcn_s_setprio(0);
    __builtin_amdgcn_sched_barrier(0);     // keep write-late truly late
    if (kt < 3) WRITE_A((kt + 1) & 1);     // cvt+ds_write into other buffer
    __syncthreads();   // drains B gloads; A-writes visible; safe buffer swap
  }
#undef LOAD_A
#undef WRITE_A
#undef STAGE_B

  // ---- epilogue: C/D layout col = lane&15, row = (lane>>4)*4 + r ----
  // store to chunked P[bb][tg][h][8t]; one f16x4 per fragment per lane.
  const int col = lane & 15;
  const int rbase = (lane >> 4) * 4;
#pragma unroll
  for (int w = 0; w < 3; ++w) {
    f16* P = (w == 0) ? Pr : ((w == 1) ? Pz : Ph);
#pragma unroll
    for (int mi = 0; mi < 4; ++mi) {
      int m = m0 + wr * 64 + mi * 16 + rbase;
      int bbl = m >> 9;
      int t = m & 511;
      size_t base = ((size_t)bbl * 64 + (t >> 3)) * 4096 + (t & 7);
#pragma unroll
      for (int ni = 0; ni < 2; ++ni) {
        int hcol = n0 + wc * 32 + ni * 16 + col;
        f16x4 v;
#pragma unroll
        for (int r = 0; r < 4; ++r) v[r] = (f16)acc[w][mi][ni][r];
        *(f16x4*)&P[base + (size_t)hcol * 8] = v;
      }
    }
  }
}

// ---------------- kernel 3: recurrent scan ----------------
// One thread per (batch, hidden) chain. P is [bb][tg][h][8t]: lane i reads
// 16B at stride 16B -> perfectly coalesced. Quad-buffered, 3 groups ahead.
__global__ void __launch_bounds__(256) brc_scan(
    const f16* __restrict__ Pr, const f16* __restrict__ Pz, const f16* __restrict__ Ph,
    const float* __restrict__ h0, const float* __restrict__ mr, const float* __restrict__ mz,
    const float* __restrict__ br, const float* __restrict__ bz,
    float* __restrict__ out, int b0) {
  int gid = blockIdx.x * 256 + threadIdx.x;   // 0 .. bc*512-1
  int bb = gid >> 9;
  int i = gid & 511;
  float h = h0[((size_t)(b0 + bb) << 9) + i];
  // folded constants (see R2):
  float mrc = 2.0f * mr[i], mzc = -mz[i];
  float br2 = 2.0f * br[i], nbz = -bz[i];
  size_t pbase = ((size_t)bb << 18) + (size_t)i * 8;   // bb*64*4096 + i*8 halfs
  const f16* prp = Pr + pbase;
  const f16* pzp = Pz + pbase;
  const f16* php = Ph + pbase;
  float* op = out + (((size_t)(b0 + bb)) << 18) + i;

  f16x8 Ar, Az, Ah, Br_, Bz_, Bh_, Cr, Cz, Ch, Dr, Dz, Dh;

#define LOADG(R, Z, Hh, g)                                              \
  do {                                                                  \
    R  = *(const f16x8*)(prp + ((size_t)(g) << 12));                    \
    Z  = *(const f16x8*)(pzp + ((size_t)(g) << 12));                    \
    Hh = *(const f16x8*)(php + ((size_t)(g) << 12));                    \
  } while (0)

#define STEP8(R, Z, Hh, g)                                              \
  do {                                                                  \
    _Pragma("unroll") for (int j = 0; j < 8; ++j) {                     \
      float prs = fmaf((float)R[j], 2.0f, br2);                         \
      float pzs = fmaf((float)Z[j], -1.0f, nbz);                        \
      float ph2 = (float)Hh[j] * 2.0f;                                  \
      float er = __expf(fmaf(h, mrc, prs));                             \
      float r  = fmaf(-2.0f, rcpf(er + 1.0f), 2.0f);                    \
      float ez = __expf(fmaf(h, mzc, pzs));                             \
      float z  = rcpf(1.0f + ez);                                       \
      float h2 = h + h;                                                 \
      float ec = __expf(fmaf(r, h2, ph2));                              \
      float cd = fmaf(-2.0f, rcpf(ec + 1.0f), 1.0f);                    \
      h = fmaf(z, h - cd, cd);                                          \
      __builtin_nontemporal_store(h, op + ((size_t)((g) * 8 + j) << 9)); \
    }                                                                   \
  } while (0)

  LOADG(Ar, Az, Ah, 0);
  LOADG(Br_, Bz_, Bh_, 1);
  LOADG(Cr, Cz, Ch, 2);
  for (int g = 0; g < 64; g += 4) {
    LOADG(Dr, Dz, Dh, g + 3);
    STEP8(Ar, Az, Ah, g);
    if (g + 4 < 64) LOADG(Ar, Az, Ah, g + 4);
    STEP8(Br_, Bz_, Bh_, g + 1);
    if (g + 5 < 64) LOADG(Br_, Bz_, Bh_, g + 5);
    STEP8(Cr, Cz, Ch, g + 2);
    if (g + 6 < 64) LOADG(Cr, Cz, Ch, g + 6);
    STEP8(Dr, Dz, Dh, g + 3);
  }
#undef LOADG
#undef STEP8
}

// ---------------- launch ----------------
extern "C" void kernel_launch(void* const* d_in, const int* in_sizes, int n_in,
                              void* d_out, int out_size, void* d_ws, size_t ws_size,
                              hipStream_t stream) {
  const float* x  = (const float*)d_in[0];
  const float* h0 = (const float*)d_in[1];
  const float* kr = (const float*)d_in[2];
  const float* kz = (const float*)d_in[3];
  const float* kh = (const float*)d_in[4];
  const float* mr = (const float*)d_in[5];
  const float* mz = (const float*)d_in[6];
  const float* br = (const float*)d_in[7];
  const float* bz = (const float*)d_in[8];
  float* out = (float*)d_out;

  f16* ws = (f16*)d_ws;

  // per-batch ws need (bytes): pr/pz/ph = 3*524288 = 1572864
  size_t avail = ws_size > 786432 ? ws_size - 786432 : 0;
  int Bc = (int)(avail / 1572864ull);
  if (Bc < 1) Bc = 1;
  if (Bc > B_TOT) Bc = B_TOT;

  cvt_w<<<1536, 256, 0, stream>>>(kr, kz, kh, ws);

  for (int b0 = 0; b0 < B_TOT; b0 += Bc) {
    int bc = (Bc < B_TOT - b0) ? Bc : (B_TOT - b0);
    f16* Pr = ws + 393216;
    f16* Pz = Pr + (size_t)bc * 262144;
    f16* Ph = Pz + (size_t)bc * 262144;

    brc_gemm3<<<bc * 32, 256, 0, stream>>>(
        x + (size_t)b0 * 131072, ws, ws + 131072, ws + 262144,
        Pr, Pz, Ph, bc * 4);
    brc_scan<<<bc * 2, 256, 0, stream>>>(Pr, Pz, Ph, h0, mr, mz, br, bz, out, b0);
  }
}

// Round 6
// 170.448 us; speedup vs baseline: 1.1257x; 1.1257x over previous
//
#include <hip/hip_runtime.h>

typedef _Float16 f16;
typedef _Float16 f16x8 __attribute__((ext_vector_type(8)));
typedef _Float16 f16x4 __attribute__((ext_vector_type(4)));
typedef float f32x4 __attribute__((ext_vector_type(4)));

#define B_TOT 128
#define T_LEN 512
#define D_DIM 256
#define H_DIM 512

// ---------------- helpers ----------------
__device__ __forceinline__ void gload_lds16(const void* g, void* l) {
  __builtin_amdgcn_global_load_lds(
      (const __attribute__((address_space(1))) void*)g,
      (__attribute__((address_space(3))) void*)l, 16, 0, 0);
}

__device__ __forceinline__ float rcpf(float x) { return __builtin_amdgcn_rcpf(x); }

// ---------------- kernel 1: weight convert + transpose ----------------
__global__ void __launch_bounds__(256) cvt_w(const float* __restrict__ Wr,
                                             const float* __restrict__ Wz,
                                             const float* __restrict__ Wh,
                                             f16* __restrict__ Wt) {
  int idx = blockIdx.x * 256 + threadIdx.x;      // < 3*131072
  int w = idx >> 17;
  int rem = idx & 131071;
  int n = rem >> 8;
  int k = rem & 255;
  const float* W = (w == 0) ? Wr : ((w == 1) ? Wz : Wh);
  Wt[(size_t)w * 131072 + n * 256 + k] = (f16)W[k * 512 + n];
}

// ---------------- kernel 2: x convert f32 -> f16 ----------------
__global__ void __launch_bounds__(256) cvt_x(const float4* __restrict__ in,
                                             f16x4* __restrict__ out) {
  int idx = blockIdx.x * 256 + threadIdx.x;
  float4 v = in[idx];
  f16x4 o;
  o[0] = (f16)v.x; o[1] = (f16)v.y; o[2] = (f16)v.z; o[3] = (f16)v.w;
  out[idx] = o;
}

// ---------------- kernel 3: fused 3-weight GEMM, counted-vmcnt pipeline ----
// X [M][256] f16, Wt [512][256] f16 (pre-transposed).
// P output layout CHUNKED: P[bb][tg(64)][h(512)][8t] f16.
// BM=128, BN=64 (x3 weights), BK=32, 8 K-iterations.
// LDS per buffer (20 KB): A [p(4)][128 rows][16B], B [w(3)][p(4)][64][16B].
// Double-buffered, depth-2 prefetch, raw s_barrier + counted vmcnt (T3/T4):
// each wave issues exactly 5 gload_lds per tile, so vmcnt(5) == "next tile
// still in flight, current tile landed". Never vmcnt(0) until the last iter.
__global__ void __launch_bounds__(256) brc_gemm3(
    const f16* __restrict__ X,
    const f16* __restrict__ Wr, const f16* __restrict__ Wz, const f16* __restrict__ Wh,
    f16* __restrict__ Pr, f16* __restrict__ Pz, f16* __restrict__ Ph,
    int Mtiles) {
  __shared__ char lds[40960];          // 2 x 20 KB buffers -> 4 blocks/CU
  const int tid = threadIdx.x;
  const int wid = tid >> 6, lane = tid & 63;
  const int bid = blockIdx.x;
  const int lid = (bid & 7) * Mtiles + (bid >> 3);   // grid = Mtiles*8, bijective
  const int mt = lid >> 3, nt = lid & 7;             // m-major: 8 lids share mt
  const int m0 = mt * 128, n0 = nt * 64;
  const int wr = wid >> 1, wc = wid & 1;             // 2x2 waves, tile 64x32

  const char* Xc  = (const char*)X + (size_t)m0 * 512;
  const char* WrC = (const char*)Wr + (size_t)n0 * 512;
  const char* WzC = (const char*)Wz + (size_t)n0 * 512;
  const char* WhC = (const char*)Wh + (size_t)n0 * 512;

  f32x4 acc[3][4][2] = {};

  // stage K-tile kt (0..7) into buffer buf: 5 gload_lds per thread,
  // exactly 5 per WAVE (vmcnt bookkeeping relies on this).
#define STAGE(kt, buf)                                                        \
  do {                                                                        \
    char* lb_ = lds + (buf) * 20480;                                          \
    _Pragma("unroll") for (int c = 0; c < 2; ++c) {  /* A: 8 chunks */        \
      int id_ = c * 4 + wid, p_ = id_ >> 1, rh_ = id_ & 1;                    \
      gload_lds16(Xc + ((size_t)(rh_ * 64 + lane)) * 512 + (kt) * 64 + p_ * 16, \
                  lb_ + p_ * 2048 + rh_ * 1024);                              \
    }                                                                         \
    _Pragma("unroll") for (int j = 0; j < 3; ++j) {  /* B: 12 chunks */       \
      int e_ = wid * 3 + j, w3_ = e_ >> 2, p_ = e_ & 3;                       \
      const char* W_ = (w3_ == 0) ? WrC : ((w3_ == 1) ? WzC : WhC);           \
      gload_lds16(W_ + (size_t)lane * 512 + (kt) * 64 + p_ * 16,              \
                  lb_ + 8192 + w3_ * 4096 + p_ * 1024);                       \
    }                                                                         \
  } while (0)

#define WAITV(n) asm volatile("s_waitcnt vmcnt(" #n ")" ::: "memory")

  STAGE(0, 0);
  STAGE(1, 1);

  const int kq = lane >> 4, rl = lane & 15;
#pragma unroll
  for (int kt = 0; kt < 8; ++kt) {
    if (kt < 7) { WAITV(5); } else { WAITV(0); }   // tile kt landed (wave-wide)
    __builtin_amdgcn_s_barrier();                  // raw: no vmcnt(0) drain
    __builtin_amdgcn_sched_barrier(0);             // no ds_read hoisting above
    const char* lb = lds + (kt & 1) * 20480;
    __builtin_amdgcn_s_setprio(1);
    f16x8 a[4], b[3][2];
#pragma unroll
    for (int mi = 0; mi < 4; ++mi)
      a[mi] = *(const f16x8*)(lb + kq * 2048 + (wr * 64 + mi * 16 + rl) * 16);
#pragma unroll
    for (int w = 0; w < 3; ++w)
#pragma unroll
      for (int ni = 0; ni < 2; ++ni)
        b[w][ni] = *(const f16x8*)(lb + 8192 + w * 4096 + kq * 1024 +
                                   (wc * 32 + ni * 16 + rl) * 16);
#pragma unroll
    for (int w = 0; w < 3; ++w)
#pragma unroll
      for (int mi = 0; mi < 4; ++mi)
#pragma unroll
        for (int ni = 0; ni < 2; ++ni)
          acc[w][mi][ni] = __builtin_amdgcn_mfma_f32_16x16x32_f16(
              a[mi], b[w][ni], acc[w][mi][ni], 0, 0, 0);
    __builtin_amdgcn_s_setprio(0);
    __builtin_amdgcn_sched_barrier(0);
    __builtin_amdgcn_s_barrier();                  // all waves done reading buf
    if (kt + 2 < 8) STAGE(kt + 2, kt & 1);         // refill the freed buffer
  }
#undef STAGE
#undef WAITV

  // ---- epilogue: C/D layout col = lane&15, row = (lane>>4)*4 + r ----
  const int col = lane & 15;
  const int rbase = (lane >> 4) * 4;
#pragma unroll
  for (int w = 0; w < 3; ++w) {
    f16* P = (w == 0) ? Pr : ((w == 1) ? Pz : Ph);
#pragma unroll
    for (int mi = 0; mi < 4; ++mi) {
      int m = m0 + wr * 64 + mi * 16 + rbase;
      int bbl = m >> 9;
      int t = m & 511;
      size_t base = ((size_t)bbl * 64 + (t >> 3)) * 4096 + (t & 7);
#pragma unroll
      for (int ni = 0; ni < 2; ++ni) {
        int hcol = n0 + wc * 32 + ni * 16 + col;
        f16x4 v;
#pragma unroll
        for (int r = 0; r < 4; ++r) v[r] = (f16)acc[w][mi][ni][r];
        *(f16x4*)&P[base + (size_t)hcol * 8] = v;
      }
    }
  }
}

// ---------------- kernel 4: recurrent scan ----------------
__global__ void __launch_bounds__(256) brc_scan(
    const f16* __restrict__ Pr, const f16* __restrict__ Pz, const f16* __restrict__ Ph,
    const float* __restrict__ h0, const float* __restrict__ mr, const float* __restrict__ mz,
    const float* __restrict__ br, const float* __restrict__ bz,
    float* __restrict__ out, int b0) {
  int gid = blockIdx.x * 256 + threadIdx.x;   // 0 .. bc*512-1
  int bb = gid >> 9;
  int i = gid & 511;
  float h = h0[((size_t)(b0 + bb) << 9) + i];
  float mrc = 2.0f * mr[i], mzc = -mz[i];
  float br2 = 2.0f * br[i], nbz = -bz[i];
  size_t pbase = ((size_t)bb << 18) + (size_t)i * 8;
  const f16* prp = Pr + pbase;
  const f16* pzp = Pz + pbase;
  const f16* php = Ph + pbase;
  float* op = out + (((size_t)(b0 + bb)) << 18) + i;

  f16x8 Ar, Az, Ah, Br_, Bz_, Bh_, Cr, Cz, Ch, Dr, Dz, Dh;

#define LOADG(R, Z, Hh, g)                                              \
  do {                                                                  \
    R  = *(const f16x8*)(prp + ((size_t)(g) << 12));                    \
    Z  = *(const f16x8*)(pzp + ((size_t)(g) << 12));                    \
    Hh = *(const f16x8*)(php + ((size_t)(g) << 12));                    \
  } while (0)

#define STEP8(R, Z, Hh, g)                                              \
  do {                                                                  \
    _Pragma("unroll") for (int j = 0; j < 8; ++j) {                     \
      float prs = fmaf((float)R[j], 2.0f, br2);                         \
      float pzs = fmaf((float)Z[j], -1.0f, nbz);                        \
      float ph2 = (float)Hh[j] * 2.0f;                                  \
      float er = __expf(fmaf(h, mrc, prs));                             \
      float r  = fmaf(-2.0f, rcpf(er + 1.0f), 2.0f);                    \
      float ez = __expf(fmaf(h, mzc, pzs));                             \
      float z  = rcpf(1.0f + ez);                                       \
      float h2 = h + h;                                                 \
      float ec = __expf(fmaf(r, h2, ph2));                              \
      float cd = fmaf(-2.0f, rcpf(ec + 1.0f), 1.0f);                    \
      h = fmaf(z, h - cd, cd);                                          \
      __builtin_nontemporal_store(h, op + ((size_t)((g) * 8 + j) << 9)); \
    }                                                                   \
  } while (0)

  LOADG(Ar, Az, Ah, 0);
  LOADG(Br_, Bz_, Bh_, 1);
  LOADG(Cr, Cz, Ch, 2);
  for (int g = 0; g < 64; g += 4) {
    LOADG(Dr, Dz, Dh, g + 3);
    STEP8(Ar, Az, Ah, g);
    if (g + 4 < 64) LOADG(Ar, Az, Ah, g + 4);
    STEP8(Br_, Bz_, Bh_, g + 1);
    if (g + 5 < 64) LOADG(Br_, Bz_, Bh_, g + 5);
    STEP8(Cr, Cz, Ch, g + 2);
    if (g + 6 < 64) LOADG(Cr, Cz, Ch, g + 6);
    STEP8(Dr, Dz, Dh, g + 3);
  }
#undef LOADG
#undef STEP8
}

// ---------------- launch ----------------
extern "C" void kernel_launch(void* const* d_in, const int* in_sizes, int n_in,
                              void* d_out, int out_size, void* d_ws, size_t ws_size,
                              hipStream_t stream) {
  const float* x  = (const float*)d_in[0];
  const float* h0 = (const float*)d_in[1];
  const float* kr = (const float*)d_in[2];
  const float* kz = (const float*)d_in[3];
  const float* kh = (const float*)d_in[4];
  const float* mr = (const float*)d_in[5];
  const float* mz = (const float*)d_in[6];
  const float* br = (const float*)d_in[7];
  const float* bz = (const float*)d_in[8];
  float* out = (float*)d_out;

  f16* ws = (f16*)d_ws;

  // per-batch ws need (bytes): x_f16 = 262144, pr/pz/ph = 3*524288 -> 1835008
  size_t avail = ws_size > 786432 ? ws_size - 786432 : 0;
  int Bc = (int)(avail / 1835008ull);
  if (Bc < 1) Bc = 1;
  if (Bc > B_TOT) Bc = B_TOT;

  cvt_w<<<1536, 256, 0, stream>>>(kr, kz, kh, ws);

  for (int b0 = 0; b0 < B_TOT; b0 += Bc) {
    int bc = (Bc < B_TOT - b0) ? Bc : (B_TOT - b0);
    f16* Xf = ws + 393216;
    f16* Pr = Xf + (size_t)bc * 131072;
    f16* Pz = Pr + (size_t)bc * 262144;
    f16* Ph = Pz + (size_t)bc * 262144;

    cvt_x<<<bc * 128, 256, 0, stream>>>(
        (const float4*)(x + (size_t)b0 * 131072), (f16x4*)Xf);
    brc_gemm3<<<bc * 32, 256, 0, stream>>>(Xf, ws, ws + 131072, ws + 262144,
                                           Pr, Pz, Ph, bc * 4);
    brc_scan<<<bc * 2, 256, 0, stream>>>(Pr, Pz, Ph, h0, mr, mz, br, bz, out, b0);
  }
}